// Round 4
// baseline (223.565 us; speedup 1.0000x reference)
//
#include <hip/hip_runtime.h>

typedef float f32x4 __attribute__((ext_vector_type(4)));
typedef short bf16x8 __attribute__((ext_vector_type(8)));

#define NB 8
#define NH 16
#define NSEQ 1024
#define NP 64
#define NKV 1088
#define NC 1024
#define NHD 64

__device__ __forceinline__ unsigned short f2bf(float f) {
  unsigned int u = __builtin_bit_cast(unsigned int, f);
  u += 0x7fffu + ((u >> 16) & 1u);  // RNE
  return (unsigned short)(u >> 16);
}

__device__ __forceinline__ void gload16(const void* g, void* l) {
  __builtin_amdgcn_global_load_lds((const __attribute__((address_space(1))) void*)g,
                                   (__attribute__((address_space(3))) void*)l, 16, 0, 0);
}

__device__ __forceinline__ f32x4 mfma16(bf16x8 a, bf16x8 b, f32x4 c) {
  return __builtin_amdgcn_mfma_f32_16x16x32_bf16(a, b, c, 0, 0, 0);
}

// ---------------- pack kernels ----------------
// one kernel for all three f32->bf16 conversions (x, Wqkv, Wproj)
__global__ void pack_all(const float* __restrict__ x, const float* __restrict__ wq,
                         const float* __restrict__ wp, unsigned short* __restrict__ xd,
                         unsigned short* __restrict__ wqd, unsigned short* __restrict__ wpd) {
  int i = blockIdx.x * 256 + threadIdx.x;  // 3145728 float4s total
  const float* s;
  unsigned short* d;
  int off;
  if (i < 2097152) { s = x; d = xd; off = i; }
  else if (i < 2883584) { s = wq; d = wqd; off = i - 2097152; }
  else { s = wp; d = wpd; off = i - 2883584; }
  float4 v = ((const float4*)s)[off];
  ushort4 o;
  o.x = f2bf(v.x); o.y = f2bf(v.y); o.z = f2bf(v.z); o.w = f2bf(v.w);
  ((ushort4*)d)[off] = o;
}

// prompt [B,2,P,H,hd] f32 -> Kg prefix [B,H,p<64,hd]*a (bf16), Vt prefix [B,H,hd,p<64]*a (bf16)
__global__ void prefix_pack(const float* __restrict__ prompt, unsigned short* __restrict__ Kg,
                            unsigned short* __restrict__ Vt, const float* __restrict__ alpha) {
  int i = blockIdx.x * 256 + threadIdx.x;  // 131072 total
  float a = alpha[0];
  int d4 = i & 15, p = (i >> 4) & 63, h = (i >> 10) & 15, b = i >> 14;
  const float4 kv = *(const float4*)(prompt + ((((size_t)(b * 2 + 0) * NP + p) * NH + h) * NHD + d4 * 4));
  ushort4 ko;
  ko.x = f2bf(kv.x * a); ko.y = f2bf(kv.y * a); ko.z = f2bf(kv.z * a); ko.w = f2bf(kv.w * a);
  *(ushort4*)(Kg + (((size_t)(b * NH + h) * NKV + p) * NHD + d4 * 4)) = ko;
  const float4 vv = *(const float4*)(prompt + ((((size_t)(b * 2 + 1) * NP + p) * NH + h) * NHD + d4 * 4));
  size_t vbase = ((size_t)(b * NH + h) * NHD + d4 * 4) * NKV + p;
  Vt[vbase]            = f2bf(vv.x * a);
  Vt[vbase + NKV]      = f2bf(vv.y * a);
  Vt[vbase + 2 * NKV]  = f2bf(vv.z * a);
  Vt[vbase + 3 * NKV]  = f2bf(vv.w * a);
}

// ---------------- GEMM (B^T layout: out[m,c] = sum_k A[m,k]*Bw[c,k]) ----------------
// BM=256 BN=128 BK=64, 512 threads (8 waves, 4M x 2N, wave out 64x64),
// 3-buffer LDS ring, 2-deep never-drain counted vmcnt.
// Race-freedom: stage of tile t+2 -> buf (t+2)%3 issues after the end-barrier of
// tile t-1 (that buffer's previous reader: all ds_reads retired via lgkmcnt(0)+barrier).
// RAW: per-wave vmcnt(12) leaves t+1,t+2's 12 loads in flight, forces tile t landed;
// barrier after vmcnt makes it block-wide.
template <int MODE>
__global__ __launch_bounds__(512, 1)
void gemm_bt(const unsigned short* __restrict__ A, const unsigned short* __restrict__ Bw, int K,
             int nyp,  // by-panels per XCD (ny/8)
             unsigned short* __restrict__ Qg, unsigned short* __restrict__ Kg,
             unsigned short* __restrict__ Vt,
             const float* __restrict__ alphap, const float* __restrict__ halfp,
             float* __restrict__ Cout, const float* __restrict__ bias) {
  // A bufs: 3 x 256x64 (16384 elems); B bufs: 3 x 128x64 (8192 elems)
  __shared__ __align__(16) unsigned short ldsAll[3 * 16384 + 3 * 8192];  // 144 KB
  const int tid = threadIdx.x, lane = tid & 63, wv = tid >> 6;
  const int wm = wv >> 1, wn = wv & 1;
  const int lg = lane >> 4, lr = lane & 15;
  // XCD-bijective swizzle: each XCD owns nyp consecutive B-panels (by-stripe)
  const int id = blockIdx.x;
  const int xcd = id & 7, kk0 = id >> 3;
  const int by = xcd * nyp + (kk0 >> 5);
  const int bx = kk0 & 31;

  f32x4 acc[4][4] = {};

  // staging addresses (source chunk-XOR pre-swizzle; LDS linear; read applies same XOR)
  const unsigned short* Ag[4];
  const unsigned short* Bg[2];
  int lofA[4], lofB[2];
#pragma unroll
  for (int i = 0; i < 4; ++i) {
    const int c = tid + 512 * i;          // 2048 chunks: row = c>>3 in [0,256)
    const int row = c >> 3;
    const int gch = (c & 7) ^ (row & 7);
    Ag[i] = A + (size_t)(bx * 256 + row) * K + gch * 8;
    lofA[i] = c * 16;
  }
#pragma unroll
  for (int i = 0; i < 2; ++i) {
    const int c = tid + 512 * i;          // 1024 chunks: row = c>>3 in [0,128)
    const int row = c >> 3;
    const int gch = (c & 7) ^ (row & 7);
    Bg[i] = Bw + (size_t)(by * 128 + row) * K + gch * 8;
    lofB[i] = c * 16;
  }

#define GSTAGE(t, bsel)                                                        \
  do {                                                                         \
    char* lA = (char*)ldsAll + (bsel) * 32768;                                 \
    char* lB = (char*)(ldsAll + 49152) + (bsel) * 16384;                       \
    _Pragma("unroll") for (int i = 0; i < 4; ++i)                              \
        gload16(Ag[i] + (size_t)(t) * 64, lA + lofA[i]);                       \
    _Pragma("unroll") for (int i = 0; i < 2; ++i)                              \
        gload16(Bg[i] + (size_t)(t) * 64, lB + lofB[i]);                       \
  } while (0)

  const int nst = K >> 6;  // 16
  int bcur = 0;
  GSTAGE(0, 0);
  GSTAGE(1, 1);
  for (int t = 0; t < nst; ++t) {
    const int bstg = (bcur == 0) ? 2 : bcur - 1;  // (t+2)%3
    if (t < nst - 2) {
      GSTAGE(t + 2, bstg);
      asm volatile("s_waitcnt vmcnt(12)" ::: "memory");  // t landed; t+1,t+2 in flight
    } else if (t == nst - 2) {
      asm volatile("s_waitcnt vmcnt(6)" ::: "memory");   // t landed; t+1 in flight
    } else {
      asm volatile("s_waitcnt vmcnt(0)" ::: "memory");
    }
    __builtin_amdgcn_s_barrier();
    asm volatile("" ::: "memory");

    const unsigned short* bufA = ldsAll + bcur * 16384;
    const unsigned short* bufB = ldsAll + 49152 + bcur * 8192;
#pragma unroll
    for (int kk = 0; kk < 2; ++kk) {
      bf16x8 af[4], bfm[4];
#pragma unroll
      for (int mf = 0; mf < 4; ++mf) {
        const int row = wm * 64 + mf * 16 + lr;
        const int pos = (kk * 4 + lg) ^ (row & 7);
        af[mf] = *(const bf16x8*)(bufA + row * 64 + pos * 8);
      }
#pragma unroll
      for (int nf = 0; nf < 4; ++nf) {
        const int row = wn * 64 + nf * 16 + lr;
        const int pos = (kk * 4 + lg) ^ (row & 7);
        bfm[nf] = *(const bf16x8*)(bufB + row * 64 + pos * 8);
      }
      __builtin_amdgcn_s_setprio(1);
#pragma unroll
      for (int mf = 0; mf < 4; ++mf)
#pragma unroll
        for (int nf = 0; nf < 4; ++nf)
          acc[mf][nf] = mfma16(af[mf], bfm[nf], acc[mf][nf]);
      __builtin_amdgcn_s_setprio(0);
    }

    asm volatile("s_waitcnt lgkmcnt(0)" ::: "memory");  // reads of bufcur retired
    __builtin_amdgcn_s_barrier();                       // buffer now reusable
    asm volatile("" ::: "memory");
    bcur = (bcur == 2) ? 0 : bcur + 1;
  }
#undef GSTAGE

  if constexpr (MODE == 0) {
    const int slot = (by * 128) >> 10;     // 0=q 1=k 2=v (BN=128 divides 1024)
    const int csIn = (by * 128) & 1023;
    // Q gets softmax scale folded in base-2 domain: 0.125 * log2(e)
    const float sc = (slot == 0) ? 0.18033688011112042f : (alphap[0] * halfp[0]);
#pragma unroll
    for (int mf = 0; mf < 4; ++mf) {
      const int grow0 = bx * 256 + wm * 64 + mf * 16 + lg * 4;
#pragma unroll
      for (int nf = 0; nf < 4; ++nf) {
        const int gcol = csIn + wn * 64 + nf * 16 + lr;
        const int h = gcol >> 6, d = gcol & 63;
#pragma unroll
        for (int j = 0; j < 4; ++j) {
          const int grow = grow0 + j;
          const int b = grow >> 10, nn = grow & 1023;
          const unsigned short u = f2bf(acc[mf][nf][j] * sc);
          if (slot == 0)      Qg[(((size_t)b * NH + h) * NSEQ + nn) * NHD + d] = u;
          else if (slot == 1) Kg[(((size_t)b * NH + h) * NKV + NP + nn) * NHD + d] = u;
          else                Vt[(((size_t)b * NH + h) * NHD + d) * NKV + NP + nn] = u;
        }
      }
    }
  } else {
#pragma unroll
    for (int mf = 0; mf < 4; ++mf) {
      const int grow0 = bx * 256 + wm * 64 + mf * 16 + lg * 4;
#pragma unroll
      for (int nf = 0; nf < 4; ++nf) {
        const int gcol = by * 128 + wn * 64 + nf * 16 + lr;
        const float bb = bias[gcol];
#pragma unroll
        for (int j = 0; j < 4; ++j)
          Cout[(size_t)(grow0 + j) * NC + gcol] = acc[mf][nf][j] + bb;
      }
    }
  }
}

// ---------------- flash attention (swapped QK^T, defer-max, 2-deep pipeline) ----------------
// flat grid 1024: bh = id&127 (XCD locality: same bh -> same XCD slot), qtile = id>>7
__global__ __launch_bounds__(256, 3)
void attn_fwd(const unsigned short* __restrict__ Qg, const unsigned short* __restrict__ Kg,
              const unsigned short* __restrict__ Vt, unsigned short* __restrict__ Oat) {
  __shared__ __align__(16) unsigned short Klds[2][64 * 64];
  __shared__ __align__(16) unsigned short Vlds[2][64 * 64];
  __shared__ __align__(16) unsigned short Plds[4 * 32 * 64];
  const int tid = threadIdx.x, lane = tid & 63, wv = tid >> 6;
  const int bh = blockIdx.x & 127;
  const int q0 = (blockIdx.x >> 7) * 128;
  const int lg = lane >> 4, lr = lane & 15;

  // Q as B-operand frags: lane holds Q[q = wv*32+nq*16+lr][k = kk*32+lg*8 ..+8]
  bf16x8 bq[2][2];
#pragma unroll
  for (int nq = 0; nq < 2; ++nq)
#pragma unroll
    for (int kk = 0; kk < 2; ++kk)
      bq[nq][kk] = *(const bf16x8*)(Qg + ((size_t)bh * NSEQ + q0 + wv * 32 + nq * 16 + lr) * NHD + kk * 32 + lg * 8);

  f32x4 oac[2][4] = {};
  float mrun[2] = {-1e30f, -1e30f};
  float lrun[2] = {0.f, 0.f};

  const int kr0 = tid >> 3, kc = tid & 7;
  const int sw = kc ^ (kr0 & 7);
  const unsigned short* Kgp = Kg + ((size_t)bh * NKV + kr0) * NHD + sw * 8;
  const unsigned short* Vgp = Vt + ((size_t)bh * NHD + kr0) * NKV + sw * 8;
  unsigned short* Pw = Plds + wv * 2048;

#define STAGE(t, bsel)                                                      \
  do {                                                                      \
    unsigned short* kb = &Klds[bsel][0] + wv * 512;                         \
    unsigned short* vb = &Vlds[bsel][0] + wv * 512;                         \
    gload16(Kgp + (size_t)(t) * 4096, kb);                                  \
    gload16(Kgp + (size_t)(t) * 4096 + 32 * NHD, kb + 2048);                \
    gload16(Vgp + (size_t)(t) * 64, vb);                                    \
    gload16(Vgp + (size_t)(t) * 64 + (size_t)32 * NKV, vb + 2048);          \
  } while (0)

  STAGE(0, 0);
  asm volatile("s_waitcnt vmcnt(0)" ::: "memory");
  __builtin_amdgcn_s_barrier();

  for (int t = 0; t < 17; ++t) {
    const int b = t & 1;
    if (t < 16) STAGE(t + 1, b ^ 1);

    // S^T = K Q^T : sa[mk][nq], lane holds k = mk*16+lg*4+j for q = nq*16+lr
    f32x4 sa[4][2] = {};
    __builtin_amdgcn_s_setprio(1);
#pragma unroll
    for (int kk = 0; kk < 2; ++kk) {
      bf16x8 ak[4];
#pragma unroll
      for (int mk = 0; mk < 4; ++mk) {
        const int row = mk * 16 + lr;
        const int cc = (kk * 4 + lg) ^ (row & 7);
        ak[mk] = *(const bf16x8*)(&Klds[b][0] + row * 64 + cc * 8);
      }
#pragma unroll
      for (int mk = 0; mk < 4; ++mk)
#pragma unroll
        for (int nq = 0; nq < 2; ++nq)
          sa[mk][nq] = mfma16(ak[mk], bq[nq][kk], sa[mk][nq]);
    }
    __builtin_amdgcn_s_setprio(0);

    // row-max per q (lane owns q = nq*16+lr across lg quarter of k)
    float tmx[2];
#pragma unroll
    for (int nq = 0; nq < 2; ++nq) {
      f32x4 m4 = sa[0][nq];
#pragma unroll
      for (int mk = 1; mk < 4; ++mk)
#pragma unroll
        for (int j = 0; j < 4; ++j) m4[j] = fmaxf(m4[j], sa[mk][nq][j]);
      float tm = fmaxf(fmaxf(m4[0], m4[1]), fmaxf(m4[2], m4[3]));
      tm = fmaxf(tm, __shfl_xor(tm, 16));
      tm = fmaxf(tm, __shfl_xor(tm, 32));
      tmx[nq] = tm;
    }
    // defer-max (T13): only rescale when max grows > 8 (log2 domain)
    const bool upd = !__all((tmx[0] <= mrun[0] + 8.f) && (tmx[1] <= mrun[1] + 8.f));
    if (upd) {
      const float nm0 = fmaxf(mrun[0], tmx[0]);
      const float nm1 = fmaxf(mrun[1], tmx[1]);
      const float e0 = __builtin_amdgcn_exp2f(mrun[0] - nm0);
      const float e1 = __builtin_amdgcn_exp2f(mrun[1] - nm1);
      mrun[0] = nm0; mrun[1] = nm1;
      lrun[0] *= e0; lrun[1] *= e1;
#pragma unroll
      for (int m = 0; m < 2; ++m)
#pragma unroll
        for (int j = 0; j < 4; ++j) {
          const float fe = __shfl(m ? e1 : e0, lg * 4 + j, 16);
#pragma unroll
          for (int df = 0; df < 4; ++df) oac[m][df][j] *= fe;
        }
    }
    // P = 2^(S - m), sum, packed store to per-wave LDS (chunk-XOR swizzle)
#pragma unroll
    for (int nq = 0; nq < 2; ++nq) {
#pragma unroll
      for (int mk = 0; mk < 4; ++mk)
#pragma unroll
        for (int j = 0; j < 4; ++j)
          sa[mk][nq][j] = __builtin_amdgcn_exp2f(sa[mk][nq][j] - mrun[nq]);
      f32x4 s4 = sa[0][nq];
#pragma unroll
      for (int mk = 1; mk < 4; ++mk)
#pragma unroll
        for (int j = 0; j < 4; ++j) s4[j] += sa[mk][nq][j];
      float s = (s4[0] + s4[1]) + (s4[2] + s4[3]);
      s += __shfl_xor(s, 16);
      s += __shfl_xor(s, 32);
      lrun[nq] += s;
      const int q = nq * 16 + lr;
#pragma unroll
      for (int mk = 0; mk < 4; ++mk) {
        const int c = mk * 2 + (lg >> 1);
        uint2 uu;
        uu.x = (unsigned)f2bf(sa[mk][nq][0]) | ((unsigned)f2bf(sa[mk][nq][1]) << 16);
        uu.y = (unsigned)f2bf(sa[mk][nq][2]) | ((unsigned)f2bf(sa[mk][nq][3]) << 16);
        *(uint2*)(Pw + q * 64 + ((c ^ (q & 7)) << 3) + (lg & 1) * 4) = uu;
      }
    }

    // O += P V : A = P rows q (16B contiguous after swizzle), B = V^T rows d
    __builtin_amdgcn_s_setprio(1);
#pragma unroll
    for (int kk = 0; kk < 2; ++kk) {
      bf16x8 bv[4], ap[2];
#pragma unroll
      for (int df = 0; df < 4; ++df) {
        const int d = df * 16 + lr;
        const int cc = (kk * 4 + lg) ^ (d & 7);
        bv[df] = *(const bf16x8*)(&Vlds[b][0] + d * 64 + cc * 8);
      }
#pragma unroll
      for (int m = 0; m < 2; ++m) {
        const int q = m * 16 + lr;
        const int pos = (kk * 4 + lg) ^ (q & 7);
        ap[m] = *(const bf16x8*)(Pw + q * 64 + pos * 8);
      }
#pragma unroll
      for (int m = 0; m < 2; ++m)
#pragma unroll
        for (int df = 0; df < 4; ++df)
          oac[m][df] = mfma16(ap[m], bv[df], oac[m][df]);
    }
    __builtin_amdgcn_s_setprio(0);

    asm volatile("s_waitcnt vmcnt(0)" ::: "memory");
    __builtin_amdgcn_s_barrier();
  }
#undef STAGE

  const int bidx = bh >> 4, h = bh & 15;
  const float l0 = 1.f / lrun[0], l1 = 1.f / lrun[1];
#pragma unroll
  for (int m = 0; m < 2; ++m) {
#pragma unroll
    for (int j = 0; j < 4; ++j) {
      const float fi = __shfl(m ? l1 : l0, lg * 4 + j, 16);
      const int row = q0 + wv * 32 + m * 16 + lg * 4 + j;
#pragma unroll
      for (int df = 0; df < 4; ++df) {
        const int col = h * 64 + df * 16 + lr;
        Oat[((size_t)bidx * NSEQ + row) * NC + col] = f2bf(oac[m][df][j] * fi);
      }
    }
  }
}

// ---------------- launch ----------------
extern "C" void kernel_launch(void* const* d_in, const int* in_sizes, int n_in,
                              void* d_out, int out_size, void* d_ws, size_t ws_size,
                              hipStream_t stream) {
  const float* x      = (const float*)d_in[0];
  const float* prompt = (const float*)d_in[1];
  const float* alpha  = (const float*)d_in[2];
  const float* halfa  = (const float*)d_in[3];
  const float* Wqkv   = (const float*)d_in[4];
  const float* Wproj  = (const float*)d_in[5];
  const float* bproj  = (const float*)d_in[6];
  float* out = (float*)d_out;

  unsigned short* ws    = (unsigned short*)d_ws;
  unsigned short* x_bf  = ws;
  unsigned short* w_bf  = x_bf + (size_t)8192 * 1024;
  unsigned short* wp_bf = w_bf + (size_t)3072 * 1024;
  unsigned short* Qg    = wp_bf + (size_t)1024 * 1024;
  unsigned short* Kg    = Qg + (size_t)NB * NH * NSEQ * NHD;
  unsigned short* Vt    = Kg + (size_t)NB * NH * NKV * NHD;
  unsigned short* Oat   = Vt + (size_t)NB * NH * NKV * NHD;

  pack_all<<<12288, 256, 0, stream>>>(x, Wqkv, Wproj, x_bf, w_bf, wp_bf);
  prefix_pack<<<512, 256, 0, stream>>>(prompt, Kg, Vt, alpha);

  // QKV: M=8192 N=3072 -> grid 32x24 = 768 blocks (nyp = 24/8 = 3)
  gemm_bt<0><<<768, 512, 0, stream>>>(x_bf, w_bf, 1024, 3, Qg, Kg, Vt, alpha, halfa,
                                      nullptr, nullptr);
  attn_fwd<<<1024, 256, 0, stream>>>(Qg, Kg, Vt, Oat);
  // proj: M=8192 N=1024 -> grid 32x8 = 256 blocks (nyp = 1)
  gemm_bt<1><<<256, 512, 0, stream>>>(Oat, wp_bf, 1024, 1, nullptr, nullptr, nullptr,
                                      nullptr, nullptr, out, bproj);
}

// Round 5
// 201.814 us; speedup vs baseline: 1.1078x; 1.1078x over previous
//
#include <hip/hip_runtime.h>

typedef float f32x4 __attribute__((ext_vector_type(4)));
typedef short bf16x8 __attribute__((ext_vector_type(8)));

#define NB 8
#define NH 16
#define NSEQ 1024
#define NP 64
#define NKV 1088
#define NC 1024
#define NHD 64

__device__ __forceinline__ unsigned short f2bf(float f) {
  unsigned int u = __builtin_bit_cast(unsigned int, f);
  u += 0x7fffu + ((u >> 16) & 1u);  // RNE
  return (unsigned short)(u >> 16);
}

__device__ __forceinline__ void gload16(const void* g, void* l) {
  __builtin_amdgcn_global_load_lds((const __attribute__((address_space(1))) void*)g,
                                   (__attribute__((address_space(3))) void*)l, 16, 0, 0);
}

__device__ __forceinline__ f32x4 mfma16(bf16x8 a, bf16x8 b, f32x4 c) {
  return __builtin_amdgcn_mfma_f32_16x16x32_bf16(a, b, c, 0, 0, 0);
}

// ---------------- pack kernels ----------------
__global__ void pack_all(const float* __restrict__ x, const float* __restrict__ wq,
                         const float* __restrict__ wp, unsigned short* __restrict__ xd,
                         unsigned short* __restrict__ wqd, unsigned short* __restrict__ wpd) {
  int i = blockIdx.x * 256 + threadIdx.x;  // 3145728 float4s total
  const float* s;
  unsigned short* d;
  int off;
  if (i < 2097152) { s = x; d = xd; off = i; }
  else if (i < 2883584) { s = wq; d = wqd; off = i - 2097152; }
  else { s = wp; d = wpd; off = i - 2883584; }
  float4 v = ((const float4*)s)[off];
  ushort4 o;
  o.x = f2bf(v.x); o.y = f2bf(v.y); o.z = f2bf(v.z); o.w = f2bf(v.w);
  ((ushort4*)d)[off] = o;
}

// prompt [B,2,P,H,hd] f32 -> Kg prefix [B,H,p<64,hd]*a (bf16), Vt prefix [B,H,hd,p<64]*a (bf16)
__global__ void prefix_pack(const float* __restrict__ prompt, unsigned short* __restrict__ Kg,
                            unsigned short* __restrict__ Vt, const float* __restrict__ alpha) {
  int i = blockIdx.x * 256 + threadIdx.x;  // 131072 total
  float a = alpha[0];
  int d4 = i & 15, p = (i >> 4) & 63, h = (i >> 10) & 15, b = i >> 14;
  const float4 kv = *(const float4*)(prompt + ((((size_t)(b * 2 + 0) * NP + p) * NH + h) * NHD + d4 * 4));
  ushort4 ko;
  ko.x = f2bf(kv.x * a); ko.y = f2bf(kv.y * a); ko.z = f2bf(kv.z * a); ko.w = f2bf(kv.w * a);
  *(ushort4*)(Kg + (((size_t)(b * NH + h) * NKV + p) * NHD + d4 * 4)) = ko;
  const float4 vv = *(const float4*)(prompt + ((((size_t)(b * 2 + 1) * NP + p) * NH + h) * NHD + d4 * 4));
  size_t vbase = ((size_t)(b * NH + h) * NHD + d4 * 4) * NKV + p;
  Vt[vbase]            = f2bf(vv.x * a);
  Vt[vbase + NKV]      = f2bf(vv.y * a);
  Vt[vbase + 2 * NKV]  = f2bf(vv.z * a);
  Vt[vbase + 3 * NKV]  = f2bf(vv.w * a);
}

// ---------------- QKV GEMM: 256x256 tile, 4-phase/K-tile deep pipeline ----------------
// 512 thr (8 waves 2M x 4N; wave out = rows {wm*64..+63} u {128+wm*64..+63},
// cols {wn*32..+31} u {128+wn*32..+31}).  LDS 128KB: A/B x parity x half.
// Hazards: half X(kt+2) staged exactly one end-barrier after X(kt)'s last read
// (A0 read p0 -> staged p1; B0 read p0 -> p2; B1 read p1 -> p2; A1 read p2 -> p3).
// One vmcnt(8) per K-tile: kt+2's 8 loads in flight, kt+1's landed. Never drains.
__global__ __launch_bounds__(512, 1)
void gemm_qkv(const unsigned short* __restrict__ A, const unsigned short* __restrict__ Bw,
              unsigned short* __restrict__ Qg, unsigned short* __restrict__ Kg,
              unsigned short* __restrict__ Vt,
              const float* __restrict__ alphap, const float* __restrict__ halfp) {
  const int K = 1024, NT = 16;
  __shared__ __align__(16) unsigned short lds[65536];  // A: [0,32768) elems, B: [32768,65536)
  unsigned short* ldsA = lds;
  unsigned short* ldsB = lds + 32768;
  const int tid = threadIdx.x, lane = tid & 63, wv = tid >> 6;
  const int wm = wv >> 2, wn = wv & 3;
  const int lg = lane >> 4, lr = lane & 15;
  // XCD swizzle: 384 blocks, 48/XCD; bx-outer within XCD -> per-XCD: 4 A-stripes + all 12 B-panels
  const int s = (blockIdx.x & 7) * 48 + (blockIdx.x >> 3);
  const int bx = s / 12, by = s % 12;

  // staging: half-tile = 128x64 bf16 = 1024 chunks of 16B; thread owns chunks tid, tid+512
  const int c0 = tid, c1 = tid + 512;
  const int r0 = c0 >> 3, g0 = (c0 & 7) ^ (r0 & 7);
  const int r1 = c1 >> 3, g1 = (c1 & 7) ^ (r1 & 7);
  const unsigned short* AgH[2][2];
  const unsigned short* BgH[2][2];
#pragma unroll
  for (int hf = 0; hf < 2; ++hf) {
    AgH[hf][0] = A + (size_t)(bx * 256 + hf * 128 + r0) * K + g0 * 8;
    AgH[hf][1] = A + (size_t)(bx * 256 + hf * 128 + r1) * K + g1 * 8;
    BgH[hf][0] = Bw + (size_t)(by * 256 + hf * 128 + r0) * K + g0 * 8;
    BgH[hf][1] = Bw + (size_t)(by * 256 + hf * 128 + r1) * K + g1 * 8;
  }
  const int o0 = c0 * 16, o1 = c1 * 16;  // byte offsets in slot

#define STG_A(hf, kt)                                                          \
  do {                                                                         \
    char* base = (char*)lds + ((kt) & 1) * 32768 + (hf) * 16384;               \
    gload16(AgH[hf][0] + (size_t)(kt) * 64, base + o0);                        \
    gload16(AgH[hf][1] + (size_t)(kt) * 64, base + o1);                        \
  } while (0)
#define STG_B(hf, kt)                                                          \
  do {                                                                         \
    char* base = (char*)lds + 65536 + ((kt) & 1) * 32768 + (hf) * 16384;       \
    gload16(BgH[hf][0] + (size_t)(kt) * 64, base + o0);                        \
    gload16(BgH[hf][1] + (size_t)(kt) * 64, base + o1);                        \
  } while (0)

  f32x4 acc[2][2][4][2] = {};  // [qm][qn][mf][nf]
  const int pos0 = lg ^ (lr & 7), pos1 = (4 + lg) ^ (lr & 7);

  // prologue: kt0 + kt1 fully staged; vmcnt(8) -> kt0 landed, kt1 in flight
  STG_A(0, 0); STG_B(0, 0); STG_B(1, 0); STG_A(1, 0);
  STG_A(0, 1); STG_B(0, 1); STG_B(1, 1); STG_A(1, 1);
  asm volatile("s_waitcnt vmcnt(8)" ::: "memory");
  __builtin_amdgcn_s_barrier();
  asm volatile("" ::: "memory");

#define MFMA_Q(qm, qn)                                                         \
  do {                                                                         \
    __builtin_amdgcn_s_setprio(1);                                             \
    _Pragma("unroll") for (int mf = 0; mf < 4; ++mf)                           \
    _Pragma("unroll") for (int nf = 0; nf < 2; ++nf)                           \
    _Pragma("unroll") for (int kk = 0; kk < 2; ++kk)                           \
        acc[qm][qn][mf][nf] = mfma16(af[mf][kk], bf[nf][kk], acc[qm][qn][mf][nf]); \
    __builtin_amdgcn_s_setprio(0);                                             \
  } while (0)

  for (int kt = 0; kt < NT; ++kt) {
    const int par = kt & 1;
    const unsigned short* Ap = ldsA + par * 16384;
    const unsigned short* Bp = ldsB + par * 16384;
    bf16x8 af[4][2], bf[2][2], bg[2][2];
    // ---- phase 0: read A-half0 + B-half0; MFMA acc[0][0]
#pragma unroll
    for (int mf = 0; mf < 4; ++mf) {
      const int ro = (wm * 64 + mf * 16 + lr) * 64;
      af[mf][0] = *(const bf16x8*)(Ap + ro + pos0 * 8);
      af[mf][1] = *(const bf16x8*)(Ap + ro + pos1 * 8);
    }
#pragma unroll
    for (int nf = 0; nf < 2; ++nf) {
      const int ro = (wn * 32 + nf * 16 + lr) * 64;
      bf[nf][0] = *(const bf16x8*)(Bp + ro + pos0 * 8);
      bf[nf][1] = *(const bf16x8*)(Bp + ro + pos1 * 8);
    }
    __builtin_amdgcn_s_barrier();
    asm volatile("s_waitcnt lgkmcnt(0)" ::: "memory");
    __builtin_amdgcn_sched_barrier(0);
    MFMA_Q(0, 0);
    __builtin_amdgcn_s_barrier();
    asm volatile("" ::: "memory");
    // ---- phase 1: read B-half1; stage A0(kt+2); MFMA acc[0][1]
#pragma unroll
    for (int nf = 0; nf < 2; ++nf) {
      const int ro = (wn * 32 + nf * 16 + lr) * 64;
      bg[nf][0] = *(const bf16x8*)(Bp + 8192 + ro + pos0 * 8);
      bg[nf][1] = *(const bf16x8*)(Bp + 8192 + ro + pos1 * 8);
    }
    if (kt + 2 < NT) STG_A(0, kt + 2);
    __builtin_amdgcn_s_barrier();
    asm volatile("s_waitcnt lgkmcnt(0)" ::: "memory");
    __builtin_amdgcn_sched_barrier(0);
    {
      bf16x8(*bf)[2] = bg;
      MFMA_Q(0, 1);
    }
    __builtin_amdgcn_s_barrier();
    asm volatile("" ::: "memory");
    // ---- phase 2: read A-half1; stage B0,B1(kt+2); MFMA acc[1][0]
#pragma unroll
    for (int mf = 0; mf < 4; ++mf) {
      const int ro = (wm * 64 + mf * 16 + lr) * 64;
      af[mf][0] = *(const bf16x8*)(Ap + 8192 + ro + pos0 * 8);
      af[mf][1] = *(const bf16x8*)(Ap + 8192 + ro + pos1 * 8);
    }
    if (kt + 2 < NT) { STG_B(0, kt + 2); STG_B(1, kt + 2); }
    __builtin_amdgcn_s_barrier();
    asm volatile("s_waitcnt lgkmcnt(0)" ::: "memory");
    __builtin_amdgcn_sched_barrier(0);
    MFMA_Q(1, 0);
    __builtin_amdgcn_s_barrier();
    asm volatile("" ::: "memory");
    // ---- phase 3: stage A1(kt+2); MFMA acc[1][1]; counted vmcnt; barrier
    if (kt + 2 < NT) STG_A(1, kt + 2);
    __builtin_amdgcn_s_barrier();
    asm volatile("" ::: "memory");
    {
      bf16x8(*bf)[2] = bg;
      MFMA_Q(1, 1);
    }
    if (kt < NT - 2) asm volatile("s_waitcnt vmcnt(8)" ::: "memory");
    else             asm volatile("s_waitcnt vmcnt(0)" ::: "memory");
    __builtin_amdgcn_s_barrier();
    asm volatile("" ::: "memory");
  }
#undef STG_A
#undef STG_B
#undef MFMA_Q

  // epilogue: scatter to Q / K(+64) / V^T(+64)
  const int slot = by >> 2;            // 0=q 1=k 2=v (256-col tiles never straddle)
  const int csIn = (by & 3) * 256;
  const float sc = (slot == 0) ? 0.18033688011112042f : (alphap[0] * halfp[0]);
#pragma unroll
  for (int qm = 0; qm < 2; ++qm)
#pragma unroll
    for (int qn = 0; qn < 2; ++qn)
#pragma unroll
      for (int mf = 0; mf < 4; ++mf) {
        const int grow0 = bx * 256 + qm * 128 + wm * 64 + mf * 16 + lg * 4;
#pragma unroll
        for (int nf = 0; nf < 2; ++nf) {
          const int gcol = csIn + qn * 128 + wn * 32 + nf * 16 + lr;
          const int h = gcol >> 6, d = gcol & 63;
#pragma unroll
          for (int j = 0; j < 4; ++j) {
            const int grow = grow0 + j;
            const int b = grow >> 10, nn = grow & 1023;
            const unsigned short u = f2bf(acc[qm][qn][mf][nf][j] * sc);
            if (slot == 0)      Qg[(((size_t)b * NH + h) * NSEQ + nn) * NHD + d] = u;
            else if (slot == 1) Kg[(((size_t)b * NH + h) * NKV + NP + nn) * NHD + d] = u;
            else                Vt[(((size_t)b * NH + h) * NHD + d) * NKV + NP + nn] = u;
          }
        }
      }
}

// ---------------- proj GEMM (r3-proven 128x128, BK=64 dbuf, counted vmcnt) ----------------
__global__ __launch_bounds__(256, 2)
void gemm_proj(const unsigned short* __restrict__ A, const unsigned short* __restrict__ Bw,
               float* __restrict__ Cout, const float* __restrict__ bias) {
  const int K = 1024;
  __shared__ __align__(16) unsigned short ldsA[2][128 * 64];
  __shared__ __align__(16) unsigned short ldsB[2][128 * 64];
  const int tid = threadIdx.x, lane = tid & 63, wv = tid >> 6;
  const int wr = wv >> 1, wc = wv & 1;
  const int lg = lane >> 4, lr = lane & 15;
  const int bx = blockIdx.x, by = blockIdx.y;

  f32x4 acc[4][4] = {};

  const unsigned short* Ag[4];
  const unsigned short* Bg[4];
  int ldof[4];
#pragma unroll
  for (int i = 0; i < 4; ++i) {
    const int c = tid + 256 * i;
    const int row = c >> 3;
    const int gch = (c & 7) ^ (row & 7);
    Ag[i] = A + (size_t)(bx * 128 + row) * K + gch * 8;
    Bg[i] = Bw + (size_t)(by * 128 + row) * K + gch * 8;
    ldof[i] = c * 16;
  }

#define GSTAGE(t, bsel)                                                        \
  do {                                                                         \
    char* lA = (char*)&ldsA[bsel][0];                                          \
    char* lB = (char*)&ldsB[bsel][0];                                          \
    _Pragma("unroll") for (int i = 0; i < 4; ++i)                              \
        gload16(Ag[i] + (size_t)(t) * 64, lA + ldof[i]);                       \
    _Pragma("unroll") for (int i = 0; i < 4; ++i)                              \
        gload16(Bg[i] + (size_t)(t) * 64, lB + ldof[i]);                       \
  } while (0)

  const int nst = K >> 6;  // 16
  int buf = 0;
  GSTAGE(0, 0);
  for (int t = 0; t < nst; ++t) {
    if (t < nst - 1) {
      GSTAGE(t + 1, buf ^ 1);
      asm volatile("s_waitcnt vmcnt(8)" ::: "memory");
    } else {
      asm volatile("s_waitcnt vmcnt(0)" ::: "memory");
    }
    __builtin_amdgcn_s_barrier();
    asm volatile("" ::: "memory");

#pragma unroll
    for (int kk = 0; kk < 2; ++kk) {
      bf16x8 af[4], bfm[4];
#pragma unroll
      for (int m = 0; m < 4; ++m) {
        const int row = wr * 64 + m * 16 + lr;
        const int pos = (kk * 4 + lg) ^ (row & 7);
        af[m] = *(const bf16x8*)(&ldsA[buf][0] + row * 64 + pos * 8);
      }
#pragma unroll
      for (int n = 0; n < 4; ++n) {
        const int row = wc * 64 + n * 16 + lr;
        const int pos = (kk * 4 + lg) ^ (row & 7);
        bfm[n] = *(const bf16x8*)(&ldsB[buf][0] + row * 64 + pos * 8);
      }
      __builtin_amdgcn_s_setprio(1);
#pragma unroll
      for (int m = 0; m < 4; ++m)
#pragma unroll
        for (int n = 0; n < 4; ++n)
          acc[m][n] = mfma16(af[m], bfm[n], acc[m][n]);
      __builtin_amdgcn_s_setprio(0);
    }

    asm volatile("s_waitcnt lgkmcnt(0)" ::: "memory");
    __builtin_amdgcn_s_barrier();
    asm volatile("" ::: "memory");
    buf ^= 1;
  }
#undef GSTAGE

#pragma unroll
  for (int m = 0; m < 4; ++m) {
    const int grow0 = bx * 128 + wr * 64 + m * 16 + lg * 4;
#pragma unroll
    for (int n = 0; n < 4; ++n) {
      const int gcol = by * 128 + wc * 64 + n * 16 + lr;
      const float bb = bias[gcol];
#pragma unroll
      for (int j = 0; j < 4; ++j)
        Cout[(size_t)(grow0 + j) * NC + gcol] = acc[m][n][j] + bb;
    }
  }
}

// ---------------- flash attention (swapped QK^T, defer-max, 2-deep pipeline) ----------------
// flat grid 1024: bh = id&127 (XCD locality: same bh -> same XCD slot), qtile = id>>7
__global__ __launch_bounds__(256, 3)
void attn_fwd(const unsigned short* __restrict__ Qg, const unsigned short* __restrict__ Kg,
              const unsigned short* __restrict__ Vt, unsigned short* __restrict__ Oat) {
  __shared__ __align__(16) unsigned short Klds[2][64 * 64];
  __shared__ __align__(16) unsigned short Vlds[2][64 * 64];
  __shared__ __align__(16) unsigned short Plds[4 * 32 * 64];
  const int tid = threadIdx.x, lane = tid & 63, wv = tid >> 6;
  const int bh = blockIdx.x & 127;
  const int q0 = (blockIdx.x >> 7) * 128;
  const int lg = lane >> 4, lr = lane & 15;

  // Q as B-operand frags: lane holds Q[q = wv*32+nq*16+lr][k = kk*32+lg*8 ..+8]
  bf16x8 bq[2][2];
#pragma unroll
  for (int nq = 0; nq < 2; ++nq)
#pragma unroll
    for (int kk = 0; kk < 2; ++kk)
      bq[nq][kk] = *(const bf16x8*)(Qg + ((size_t)bh * NSEQ + q0 + wv * 32 + nq * 16 + lr) * NHD + kk * 32 + lg * 8);

  f32x4 oac[2][4] = {};
  float mrun[2] = {-1e30f, -1e30f};
  float lrun[2] = {0.f, 0.f};

  const int kr0 = tid >> 3, kc = tid & 7;
  const int sw = kc ^ (kr0 & 7);
  const unsigned short* Kgp = Kg + ((size_t)bh * NKV + kr0) * NHD + sw * 8;
  const unsigned short* Vgp = Vt + ((size_t)bh * NHD + kr0) * NKV + sw * 8;
  unsigned short* Pw = Plds + wv * 2048;

#define STAGE(t, bsel)                                                      \
  do {                                                                      \
    unsigned short* kb = &Klds[bsel][0] + wv * 512;                         \
    unsigned short* vb = &Vlds[bsel][0] + wv * 512;                         \
    gload16(Kgp + (size_t)(t) * 4096, kb);                                  \
    gload16(Kgp + (size_t)(t) * 4096 + 32 * NHD, kb + 2048);                \
    gload16(Vgp + (size_t)(t) * 64, vb);                                    \
    gload16(Vgp + (size_t)(t) * 64 + (size_t)32 * NKV, vb + 2048);          \
  } while (0)

  STAGE(0, 0);
  asm volatile("s_waitcnt vmcnt(0)" ::: "memory");
  __builtin_amdgcn_s_barrier();

  for (int t = 0; t < 17; ++t) {
    const int b = t & 1;
    if (t < 16) STAGE(t + 1, b ^ 1);

    // S^T = K Q^T : sa[mk][nq], lane holds k = mk*16+lg*4+j for q = nq*16+lr
    f32x4 sa[4][2] = {};
    __builtin_amdgcn_s_setprio(1);
#pragma unroll
    for (int kk = 0; kk < 2; ++kk) {
      bf16x8 ak[4];
#pragma unroll
      for (int mk = 0; mk < 4; ++mk) {
        const int row = mk * 16 + lr;
        const int cc = (kk * 4 + lg) ^ (row & 7);
        ak[mk] = *(const bf16x8*)(&Klds[b][0] + row * 64 + cc * 8);
      }
#pragma unroll
      for (int mk = 0; mk < 4; ++mk)
#pragma unroll
        for (int nq = 0; nq < 2; ++nq)
          sa[mk][nq] = mfma16(ak[mk], bq[nq][kk], sa[mk][nq]);
    }
    __builtin_amdgcn_s_setprio(0);

    // row-max per q (lane owns q = nq*16+lr across lg quarter of k)
    float tmx[2];
#pragma unroll
    for (int nq = 0; nq < 2; ++nq) {
      f32x4 m4 = sa[0][nq];
#pragma unroll
      for (int mk = 1; mk < 4; ++mk)
#pragma unroll
        for (int j = 0; j < 4; ++j) m4[j] = fmaxf(m4[j], sa[mk][nq][j]);
      float tm = fmaxf(fmaxf(m4[0], m4[1]), fmaxf(m4[2], m4[3]));
      tm = fmaxf(tm, __shfl_xor(tm, 16));
      tm = fmaxf(tm, __shfl_xor(tm, 32));
      tmx[nq] = tm;
    }
    // defer-max (T13): only rescale when max grows > 8 (log2 domain)
    const bool upd = !__all((tmx[0] <= mrun[0] + 8.f) && (tmx[1] <= mrun[1] + 8.f));
    if (upd) {
      const float nm0 = fmaxf(mrun[0], tmx[0]);
      const float nm1 = fmaxf(mrun[1], tmx[1]);
      const float e0 = __builtin_amdgcn_exp2f(mrun[0] - nm0);
      const float e1 = __builtin_amdgcn_exp2f(mrun[1] - nm1);
      mrun[0] = nm0; mrun[1] = nm1;
      lrun[0] *= e0; lrun[1] *= e1;
#pragma unroll
      for (int m = 0; m < 2; ++m)
#pragma unroll
        for (int j = 0; j < 4; ++j) {
          const float fe = __shfl(m ? e1 : e0, lg * 4 + j, 16);
#pragma unroll
          for (int df = 0; df < 4; ++df) oac[m][df][j] *= fe;
        }
    }
    // P = 2^(S - m), sum, packed store to per-wave LDS (chunk-XOR swizzle)
#pragma unroll
    for (int nq = 0; nq < 2; ++nq) {
#pragma unroll
      for (int mk = 0; mk < 4; ++mk)
#pragma unroll
        for (int j = 0; j < 4; ++j)
          sa[mk][nq][j] = __builtin_amdgcn_exp2f(sa[mk][nq][j] - mrun[nq]);
      f32x4 s4 = sa[0][nq];
#pragma unroll
      for (int mk = 1; mk < 4; ++mk)
#pragma unroll
        for (int j = 0; j < 4; ++j) s4[j] += sa[mk][nq][j];
      float s = (s4[0] + s4[1]) + (s4[2] + s4[3]);
      s += __shfl_xor(s, 16);
      s += __shfl_xor(s, 32);
      lrun[nq] += s;
      const int q = nq * 16 + lr;
#pragma unroll
      for (int mk = 0; mk < 4; ++mk) {
        const int c = mk * 2 + (lg >> 1);
        uint2 uu;
        uu.x = (unsigned)f2bf(sa[mk][nq][0]) | ((unsigned)f2bf(sa[mk][nq][1]) << 16);
        uu.y = (unsigned)f2bf(sa[mk][nq][2]) | ((unsigned)f2bf(sa[mk][nq][3]) << 16);
        *(uint2*)(Pw + q * 64 + ((c ^ (q & 7)) << 3) + (lg & 1) * 4) = uu;
      }
    }

    // O += P V : A = P rows q (16B contiguous after swizzle), B = V^T rows d
    __builtin_amdgcn_s_setprio(1);
#pragma unroll
    for (int kk = 0; kk < 2; ++kk) {
      bf16x8 bv[4], ap[2];
#pragma unroll
      for (int df = 0; df < 4; ++df) {
        const int d = df * 16 + lr;
        const int cc = (kk * 4 + lg) ^ (d & 7);
        bv[df] = *(const bf16x8*)(&Vlds[b][0] + d * 64 + cc * 8);
      }
#pragma unroll
      for (int m = 0; m < 2; ++m) {
        const int q = m * 16 + lr;
        const int pos = (kk * 4 + lg) ^ (q & 7);
        ap[m] = *(const bf16x8*)(Pw + q * 64 + pos * 8);
      }
#pragma unroll
      for (int m = 0; m < 2; ++m)
#pragma unroll
        for (int df = 0; df < 4; ++df)
          oac[m][df] = mfma16(ap[m], bv[df], oac[m][df]);
    }
    __builtin_amdgcn_s_setprio(0);

    asm volatile("s_waitcnt vmcnt(0)" ::: "memory");
    __builtin_amdgcn_s_barrier();
  }
#undef STAGE

  const int bidx = bh >> 4, h = bh & 15;
  const float l0 = 1.f / lrun[0], l1 = 1.f / lrun[1];
#pragma unroll
  for (int m = 0; m < 2; ++m) {
#pragma unroll
    for (int j = 0; j < 4; ++j) {
      const float fi = __shfl(m ? l1 : l0, lg * 4 + j, 16);
      const int row = q0 + wv * 32 + m * 16 + lg * 4 + j;
#pragma unroll
      for (int df = 0; df < 4; ++df) {
        const int col = h * 64 + df * 16 + lr;
        Oat[((size_t)bidx * NSEQ + row) * NC + col] = f2bf(oac[m][df][j] * fi);
      }
    }
  }
}

// ---------------- launch ----------------
extern "C" void kernel_launch(void* const* d_in, const int* in_sizes, int n_in,
                              void* d_out, int out_size, void* d_ws, size_t ws_size,
                              hipStream_t stream) {
  const float* x      = (const float*)d_in[0];
  const float* prompt = (const float*)d_in[1];
  const float* alpha  = (const float*)d_in[2];
  const float* halfa  = (const float*)d_in[3];
  const float* Wqkv   = (const float*)d_in[4];
  const float* Wproj  = (const float*)d_in[5];
  const float* bproj  = (const float*)d_in[6];
  float* out = (float*)d_out;

  unsigned short* ws    = (unsigned short*)d_ws;
  unsigned short* x_bf  = ws;
  unsigned short* w_bf  = x_bf + (size_t)8192 * 1024;
  unsigned short* wp_bf = w_bf + (size_t)3072 * 1024;
  unsigned short* Qg    = wp_bf + (size_t)1024 * 1024;
  unsigned short* Kg    = Qg + (size_t)NB * NH * NSEQ * NHD;
  unsigned short* Vt    = Kg + (size_t)NB * NH * NKV * NHD;
  unsigned short* Oat   = Vt + (size_t)NB * NH * NKV * NHD;

  pack_all<<<12288, 256, 0, stream>>>(x, Wqkv, Wproj, x_bf, w_bf, wp_bf);
  prefix_pack<<<512, 256, 0, stream>>>(prompt, Kg, Vt, alpha);

  // QKV: M=8192 N=3072 -> 32 x 12 = 384 blocks of 256^2
  gemm_qkv<<<384, 512, 0, stream>>>(x_bf, w_bf, Qg, Kg, Vt, alpha, halfa);
  attn_fwd<<<1024, 256, 0, stream>>>(Qg, Kg, Vt, Oat);
  // proj: M=8192 N=1024 -> 64 x 8 = 512 blocks of 128^2
  gemm_proj<<<dim3(64, 8), 256, 0, stream>>>(Oat, wp_bf, out, bproj);
}

// Round 6
// 191.707 us; speedup vs baseline: 1.1662x; 1.0527x over previous
//
#include <hip/hip_runtime.h>

typedef float f32x4 __attribute__((ext_vector_type(4)));
typedef short bf16x8 __attribute__((ext_vector_type(8)));

#define NB 8
#define NH 16
#define NSEQ 1024
#define NP 64
#define NKV 1088
#define NC 1024
#define NHD 64

__device__ __forceinline__ unsigned short f2bf(float f) {
  unsigned int u = __builtin_bit_cast(unsigned int, f);
  u += 0x7fffu + ((u >> 16) & 1u);  // RNE
  return (unsigned short)(u >> 16);
}

__device__ __forceinline__ void gload16(const void* g, void* l) {
  __builtin_amdgcn_global_load_lds((const __attribute__((address_space(1))) void*)g,
                                   (__attribute__((address_space(3))) void*)l, 16, 0, 0);
}

__device__ __forceinline__ f32x4 mfma16(bf16x8 a, bf16x8 b, f32x4 c) {
  return __builtin_amdgcn_mfma_f32_16x16x32_bf16(a, b, c, 0, 0, 0);
}

// ---------------- pack kernels ----------------
__global__ void pack_all(const float* __restrict__ x, const float* __restrict__ wq,
                         const float* __restrict__ wp, unsigned short* __restrict__ xd,
                         unsigned short* __restrict__ wqd, unsigned short* __restrict__ wpd) {
  int i = blockIdx.x * 256 + threadIdx.x;  // 3145728 float4s total
  const float* s;
  unsigned short* d;
  int off;
  if (i < 2097152) { s = x; d = xd; off = i; }
  else if (i < 2883584) { s = wq; d = wqd; off = i - 2097152; }
  else { s = wp; d = wpd; off = i - 2883584; }
  float4 v = ((const float4*)s)[off];
  ushort4 o;
  o.x = f2bf(v.x); o.y = f2bf(v.y); o.z = f2bf(v.z); o.w = f2bf(v.w);
  ((ushort4*)d)[off] = o;
}

// prompt [B,2,P,H,hd] f32 -> Kg prefix [B,H,p<64,hd]*a (bf16), Vt prefix [B,H,hd,p<64]*a (bf16)
__global__ void prefix_pack(const float* __restrict__ prompt, unsigned short* __restrict__ Kg,
                            unsigned short* __restrict__ Vt, const float* __restrict__ alpha) {
  int i = blockIdx.x * 256 + threadIdx.x;  // 131072 total
  float a = alpha[0];
  int d4 = i & 15, p = (i >> 4) & 63, h = (i >> 10) & 15, b = i >> 14;
  const float4 kv = *(const float4*)(prompt + ((((size_t)(b * 2 + 0) * NP + p) * NH + h) * NHD + d4 * 4));
  ushort4 ko;
  ko.x = f2bf(kv.x * a); ko.y = f2bf(kv.y * a); ko.z = f2bf(kv.z * a); ko.w = f2bf(kv.w * a);
  *(ushort4*)(Kg + (((size_t)(b * NH + h) * NKV + p) * NHD + d4 * 4)) = ko;
  const float4 vv = *(const float4*)(prompt + ((((size_t)(b * 2 + 1) * NP + p) * NH + h) * NHD + d4 * 4));
  size_t vbase = ((size_t)(b * NH + h) * NHD + d4 * 4) * NKV + p;
  Vt[vbase]            = f2bf(vv.x * a);
  Vt[vbase + NKV]      = f2bf(vv.y * a);
  Vt[vbase + 2 * NKV]  = f2bf(vv.z * a);
  Vt[vbase + 3 * NKV]  = f2bf(vv.w * a);
}

// ---------------- GEMM (B^T layout: out[m,c] = sum_k A[m,k]*Bw[c,k]) ----------------
// r3-proven: BK=64, double-buffered LDS, counted-vmcnt 2-phase pipeline.
template <int MODE>
__global__ __launch_bounds__(256, 2)
void gemm_bt(const unsigned short* __restrict__ A, const unsigned short* __restrict__ Bw, int K,
             unsigned short* __restrict__ Qg, unsigned short* __restrict__ Kg,
             unsigned short* __restrict__ Vt,
             const float* __restrict__ alphap, const float* __restrict__ halfp,
             float* __restrict__ Cout, const float* __restrict__ bias) {
  __shared__ __align__(16) unsigned short ldsA[2][128 * 64];
  __shared__ __align__(16) unsigned short ldsB[2][128 * 64];
  const int tid = threadIdx.x, lane = tid & 63, wv = tid >> 6;
  const int wr = wv >> 1, wc = wv & 1;
  const int lg = lane >> 4, lr = lane & 15;
  const int bx = blockIdx.x, by = blockIdx.y;

  f32x4 acc[4][4] = {};

  const unsigned short* Ag[4];
  const unsigned short* Bg[4];
  int ldof[4];
#pragma unroll
  for (int i = 0; i < 4; ++i) {
    const int c = tid + 256 * i;
    const int row = c >> 3;
    const int gch = (c & 7) ^ (row & 7);
    Ag[i] = A + (size_t)(bx * 128 + row) * K + gch * 8;
    Bg[i] = Bw + (size_t)(by * 128 + row) * K + gch * 8;
    ldof[i] = c * 16;
  }

#define GSTAGE(t, bsel)                                                        \
  do {                                                                         \
    char* lA = (char*)&ldsA[bsel][0];                                          \
    char* lB = (char*)&ldsB[bsel][0];                                          \
    _Pragma("unroll") for (int i = 0; i < 4; ++i)                              \
        gload16(Ag[i] + (size_t)(t) * 64, lA + ldof[i]);                       \
    _Pragma("unroll") for (int i = 0; i < 4; ++i)                              \
        gload16(Bg[i] + (size_t)(t) * 64, lB + ldof[i]);                       \
  } while (0)

  const int nst = K >> 6;  // 16
  int buf = 0;
  GSTAGE(0, 0);
  for (int t = 0; t < nst; ++t) {
    if (t < nst - 1) {
      GSTAGE(t + 1, buf ^ 1);
      asm volatile("s_waitcnt vmcnt(8)" ::: "memory");  // t landed; t+1 in flight
    } else {
      asm volatile("s_waitcnt vmcnt(0)" ::: "memory");
    }
    __builtin_amdgcn_s_barrier();
    asm volatile("" ::: "memory");

#pragma unroll
    for (int kk = 0; kk < 2; ++kk) {
      bf16x8 af[4], bfm[4];
#pragma unroll
      for (int m = 0; m < 4; ++m) {
        const int row = wr * 64 + m * 16 + lr;
        const int pos = (kk * 4 + lg) ^ (row & 7);
        af[m] = *(const bf16x8*)(&ldsA[buf][0] + row * 64 + pos * 8);
      }
#pragma unroll
      for (int n = 0; n < 4; ++n) {
        const int row = wc * 64 + n * 16 + lr;
        const int pos = (kk * 4 + lg) ^ (row & 7);
        bfm[n] = *(const bf16x8*)(&ldsB[buf][0] + row * 64 + pos * 8);
      }
      __builtin_amdgcn_s_setprio(1);
#pragma unroll
      for (int m = 0; m < 4; ++m)
#pragma unroll
        for (int n = 0; n < 4; ++n)
          acc[m][n] = mfma16(af[m], bfm[n], acc[m][n]);
      __builtin_amdgcn_s_setprio(0);
    }

    asm volatile("s_waitcnt lgkmcnt(0)" ::: "memory");
    __builtin_amdgcn_s_barrier();
    asm volatile("" ::: "memory");
    buf ^= 1;
  }
#undef GSTAGE

  if constexpr (MODE == 0) {
    const int slot = (by * 128) >> 10;
    const int csIn = (by * 128) & 1023;
    // Q gets softmax scale folded in base-2 domain: 0.125 * log2(e)
    const float sc = (slot == 0) ? 0.18033688011112042f : (alphap[0] * halfp[0]);
#pragma unroll
    for (int m = 0; m < 4; ++m) {
      const int grow0 = bx * 128 + wr * 64 + m * 16 + lg * 4;
#pragma unroll
      for (int n = 0; n < 4; ++n) {
        const int gcol = csIn + wc * 64 + n * 16 + lr;
        const int h = gcol >> 6, d = gcol & 63;
#pragma unroll
        for (int j = 0; j < 4; ++j) {
          const int grow = grow0 + j;
          const int b = grow >> 10, nn = grow & 1023;
          const unsigned short u = f2bf(acc[m][n][j] * sc);
          if (slot == 0)      Qg[(((size_t)b * NH + h) * NSEQ + nn) * NHD + d] = u;
          else if (slot == 1) Kg[(((size_t)b * NH + h) * NKV + NP + nn) * NHD + d] = u;
          else                Vt[(((size_t)b * NH + h) * NHD + d) * NKV + NP + nn] = u;
        }
      }
    }
  } else {
#pragma unroll
    for (int m = 0; m < 4; ++m) {
      const int grow0 = bx * 128 + wr * 64 + m * 16 + lg * 4;
#pragma unroll
      for (int n = 0; n < 4; ++n) {
        const int gcol = by * 128 + wc * 64 + n * 16 + lr;
        const float bb = bias[gcol];
#pragma unroll
        for (int j = 0; j < 4; ++j)
          Cout[(size_t)(grow0 + j) * NC + gcol] = acc[m][n][j] + bb;
      }
    }
  }
}

// ---------------- flash attention (swapped QK^T, defer-max) ----------------
// QBLK=256: 8 waves x 32 q-rows. grid 512: bh = id&127 (4 q-blocks of a bh land on
// one XCD: ids bh+128k = bh mod 8), qb = id>>7. Per-wave code identical to r2-proven.
__global__ __launch_bounds__(512, 2)
void attn_fwd(const unsigned short* __restrict__ Qg, const unsigned short* __restrict__ Kg,
              const unsigned short* __restrict__ Vt, unsigned short* __restrict__ Oat) {
  __shared__ __align__(16) unsigned short Klds[2][64 * 64];
  __shared__ __align__(16) unsigned short Vlds[2][64 * 64];
  __shared__ __align__(16) unsigned short Plds[8 * 32 * 64];
  const int tid = threadIdx.x, lane = tid & 63, wv = tid >> 6;
  const int bh = blockIdx.x & 127;
  const int q0 = (blockIdx.x >> 7) * 256;
  const int lg = lane >> 4, lr = lane & 15;

  // Q as B-operand frags: lane holds Q[q = q0+wv*32+nq*16+lr][k = kk*32+lg*8 ..+8]
  bf16x8 bq[2][2];
#pragma unroll
  for (int nq = 0; nq < 2; ++nq)
#pragma unroll
    for (int kk = 0; kk < 2; ++kk)
      bq[nq][kk] = *(const bf16x8*)(Qg + ((size_t)bh * NSEQ + q0 + wv * 32 + nq * 16 + lr) * NHD + kk * 32 + lg * 8);

  f32x4 oac[2][4] = {};
  float mrun[2] = {-1e30f, -1e30f};
  float lrun[2] = {0.f, 0.f};

  // staging: K tile 64x64 = 512 16B chunks, 1 per thread; V^T tile same.
  const int kr0 = tid >> 3, kc = tid & 7;
  const int sw = kc ^ (kr0 & 7);
  const unsigned short* Kgp = Kg + ((size_t)bh * NKV + kr0) * NHD + sw * 8;
  const unsigned short* Vgp = Vt + ((size_t)bh * NHD + kr0) * NKV + sw * 8;
  unsigned short* Pw = Plds + wv * 2048;

#define STAGE(t, bsel)                                                      \
  do {                                                                      \
    gload16(Kgp + (size_t)(t) * 4096, &Klds[bsel][0] + tid * 8);            \
    gload16(Vgp + (size_t)(t) * 64, &Vlds[bsel][0] + tid * 8);              \
  } while (0)

  STAGE(0, 0);
  asm volatile("s_waitcnt vmcnt(0)" ::: "memory");
  __builtin_amdgcn_s_barrier();

  for (int t = 0; t < 17; ++t) {
    const int b = t & 1;
    if (t < 16) STAGE(t + 1, b ^ 1);

    // S^T = K Q^T : sa[mk][nq], lane holds k = mk*16+lg*4+j for q = nq*16+lr
    f32x4 sa[4][2] = {};
    __builtin_amdgcn_s_setprio(1);
#pragma unroll
    for (int kk = 0; kk < 2; ++kk) {
      bf16x8 ak[4];
#pragma unroll
      for (int mk = 0; mk < 4; ++mk) {
        const int row = mk * 16 + lr;
        const int cc = (kk * 4 + lg) ^ (row & 7);
        ak[mk] = *(const bf16x8*)(&Klds[b][0] + row * 64 + cc * 8);
      }
#pragma unroll
      for (int mk = 0; mk < 4; ++mk)
#pragma unroll
        for (int nq = 0; nq < 2; ++nq)
          sa[mk][nq] = mfma16(ak[mk], bq[nq][kk], sa[mk][nq]);
    }
    __builtin_amdgcn_s_setprio(0);

    // row-max per q (lane owns q = nq*16+lr across lg quarter of k)
    float tmx[2];
#pragma unroll
    for (int nq = 0; nq < 2; ++nq) {
      f32x4 m4 = sa[0][nq];
#pragma unroll
      for (int mk = 1; mk < 4; ++mk)
#pragma unroll
        for (int j = 0; j < 4; ++j) m4[j] = fmaxf(m4[j], sa[mk][nq][j]);
      float tm = fmaxf(fmaxf(m4[0], m4[1]), fmaxf(m4[2], m4[3]));
      tm = fmaxf(tm, __shfl_xor(tm, 16));
      tm = fmaxf(tm, __shfl_xor(tm, 32));
      tmx[nq] = tm;
    }
    // defer-max (T13): only rescale when max grows > 8 (log2 domain)
    const bool upd = !__all((tmx[0] <= mrun[0] + 8.f) && (tmx[1] <= mrun[1] + 8.f));
    if (upd) {
      const float nm0 = fmaxf(mrun[0], tmx[0]);
      const float nm1 = fmaxf(mrun[1], tmx[1]);
      const float e0 = __builtin_amdgcn_exp2f(mrun[0] - nm0);
      const float e1 = __builtin_amdgcn_exp2f(mrun[1] - nm1);
      mrun[0] = nm0; mrun[1] = nm1;
      lrun[0] *= e0; lrun[1] *= e1;
#pragma unroll
      for (int m = 0; m < 2; ++m)
#pragma unroll
        for (int j = 0; j < 4; ++j) {
          const float fe = __shfl(m ? e1 : e0, lg * 4 + j, 16);
#pragma unroll
          for (int df = 0; df < 4; ++df) oac[m][df][j] *= fe;
        }
    }
    // P = 2^(S - m), sum, packed store to per-wave LDS (chunk-XOR swizzle)
#pragma unroll
    for (int nq = 0; nq < 2; ++nq) {
#pragma unroll
      for (int mk = 0; mk < 4; ++mk)
#pragma unroll
        for (int j = 0; j < 4; ++j)
          sa[mk][nq][j] = __builtin_amdgcn_exp2f(sa[mk][nq][j] - mrun[nq]);
      f32x4 s4 = sa[0][nq];
#pragma unroll
      for (int mk = 1; mk < 4; ++mk)
#pragma unroll
        for (int j = 0; j < 4; ++j) s4[j] += sa[mk][nq][j];
      float s = (s4[0] + s4[1]) + (s4[2] + s4[3]);
      s += __shfl_xor(s, 16);
      s += __shfl_xor(s, 32);
      lrun[nq] += s;
      const int q = nq * 16 + lr;
#pragma unroll
      for (int mk = 0; mk < 4; ++mk) {
        const int c = mk * 2 + (lg >> 1);
        uint2 uu;
        uu.x = (unsigned)f2bf(sa[mk][nq][0]) | ((unsigned)f2bf(sa[mk][nq][1]) << 16);
        uu.y = (unsigned)f2bf(sa[mk][nq][2]) | ((unsigned)f2bf(sa[mk][nq][3]) << 16);
        *(uint2*)(Pw + q * 64 + ((c ^ (q & 7)) << 3) + (lg & 1) * 4) = uu;
      }
    }

    // O += P V : A = P rows q (16B contiguous after swizzle), B = V^T rows d
    __builtin_amdgcn_s_setprio(1);
#pragma unroll
    for (int kk = 0; kk < 2; ++kk) {
      bf16x8 bv[4], ap[2];
#pragma unroll
      for (int df = 0; df < 4; ++df) {
        const int d = df * 16 + lr;
        const int cc = (kk * 4 + lg) ^ (d & 7);
        bv[df] = *(const bf16x8*)(&Vlds[b][0] + d * 64 + cc * 8);
      }
#pragma unroll
      for (int m = 0; m < 2; ++m) {
        const int q = m * 16 + lr;
        const int pos = (kk * 4 + lg) ^ (q & 7);
        ap[m] = *(const bf16x8*)(Pw + q * 64 + pos * 8);
      }
#pragma unroll
      for (int m = 0; m < 2; ++m)
#pragma unroll
        for (int df = 0; df < 4; ++df)
          oac[m][df] = mfma16(ap[m], bv[df], oac[m][df]);
    }
    __builtin_amdgcn_s_setprio(0);

    asm volatile("s_waitcnt vmcnt(0)" ::: "memory");
    __builtin_amdgcn_s_barrier();
  }
#undef STAGE

  const int bidx = bh >> 4, h = bh & 15;
  const float l0 = 1.f / lrun[0], l1 = 1.f / lrun[1];
#pragma unroll
  for (int m = 0; m < 2; ++m) {
#pragma unroll
    for (int j = 0; j < 4; ++j) {
      const float fi = __shfl(m ? l1 : l0, lg * 4 + j, 16);
      const int row = q0 + wv * 32 + m * 16 + lg * 4 + j;
#pragma unroll
      for (int df = 0; df < 4; ++df) {
        const int col = h * 64 + df * 16 + lr;
        Oat[((size_t)bidx * NSEQ + row) * NC + col] = f2bf(oac[m][df][j] * fi);
      }
    }
  }
}

// ---------------- launch ----------------
extern "C" void kernel_launch(void* const* d_in, const int* in_sizes, int n_in,
                              void* d_out, int out_size, void* d_ws, size_t ws_size,
                              hipStream_t stream) {
  const float* x      = (const float*)d_in[0];
  const float* prompt = (const float*)d_in[1];
  const float* alpha  = (const float*)d_in[2];
  const float* halfa  = (const float*)d_in[3];
  const float* Wqkv   = (const float*)d_in[4];
  const float* Wproj  = (const float*)d_in[5];
  const float* bproj  = (const float*)d_in[6];
  float* out = (float*)d_out;

  unsigned short* ws    = (unsigned short*)d_ws;
  unsigned short* x_bf  = ws;
  unsigned short* w_bf  = x_bf + (size_t)8192 * 1024;
  unsigned short* wp_bf = w_bf + (size_t)3072 * 1024;
  unsigned short* Qg    = wp_bf + (size_t)1024 * 1024;
  unsigned short* Kg    = Qg + (size_t)NB * NH * NSEQ * NHD;
  unsigned short* Vt    = Kg + (size_t)NB * NH * NKV * NHD;
  unsigned short* Oat   = Vt + (size_t)NB * NH * NKV * NHD;

  pack_all<<<12288, 256, 0, stream>>>(x, Wqkv, Wproj, x_bf, w_bf, wp_bf);
  prefix_pack<<<512, 256, 0, stream>>>(prompt, Kg, Vt, alpha);

  // QKV: M=8192 N=3072 -> 64 x 24 of 128^2 (r3-proven)
  gemm_bt<0><<<dim3(64, 24), 256, 0, stream>>>(x_bf, w_bf, 1024, Qg, Kg, Vt, alpha, halfa,
                                               nullptr, nullptr);
  attn_fwd<<<512, 512, 0, stream>>>(Qg, Kg, Vt, Oat);
  // proj: M=8192 N=1024 -> 64 x 8 of 128^2
  gemm_bt<1><<<dim3(64, 8), 256, 0, stream>>>(Oat, wp_bf, 1024, nullptr, nullptr, nullptr,
                                              nullptr, nullptr, out, bproj);
}